// Round 1
// baseline (1134.392 us; speedup 1.0000x reference)
//
#include <hip/hip_runtime.h>

// MIND-SSC loss, N=2, C=1, D=H=W=128, radius=1, dilation=2.
// Key facts used:
//  - the 6 "six" offsets are the face neighbors at +/-2 along each axis
//  - the 12 channels are all pairs of those 6 except the 3 opposite pairs
//  - ssd_c(v) = sum_{w in {-1,0,1}^3} diff2_c(clamp(v+w)), nested clamps
//  - skipping the /27 is exact up to rounding (mind/var ratio and clip
//    bounds are jointly scale-invariant)

#define DIM 128
#define HW (128 * 128)
#define DHW (128 * 128 * 128)
#define NVOX (2 * DHW)            // voxels per tensor (N=2)
#define LOSS_COUNT (2.0 * 12.0 * DHW)

__device__ __forceinline__ int clampi(int v) {
    v = v < 0 ? 0 : v;
    return v > 127 ? 127 : v;
}

// ssd[12] (un-normalized, no /27) at voxel (z,y,x); img pre-offset by n*DHW.
__device__ __forceinline__ void compute_ssd(const float* __restrict__ img,
                                            int z, int y, int x, float ssd[12]) {
    int zo[3][3], yo[3][3], xo[3][3];
#pragma unroll
    for (int w = 0; w < 3; ++w) {
        int uz = clampi(z + w - 1);
        int uy = clampi(y + w - 1);
        int ux = clampi(x + w - 1);
#pragma unroll
        for (int o = 0; o < 3; ++o) {
            zo[w][o] = clampi(uz + (o - 1) * 2) * HW;
            yo[w][o] = clampi(uy + (o - 1) * 2) * DIM;
            xo[w][o] = clampi(ux + (o - 1) * 2);
        }
    }
#pragma unroll
    for (int c = 0; c < 12; ++c) ssd[c] = 0.0f;

#pragma unroll
    for (int wz = 0; wz < 3; ++wz)
#pragma unroll
        for (int wy = 0; wy < 3; ++wy)
#pragma unroll
            for (int wx = 0; wx < 3; ++wx) {
                // 6 face-neighbor-at-2 samples around u = clamp(v + w)
                float s0 = img[zo[wz][0] + yo[wy][1] + xo[wx][1]]; // z-2
                float s1 = img[zo[wz][1] + yo[wy][1] + xo[wx][0]]; // x-2
                float s2 = img[zo[wz][1] + yo[wy][0] + xo[wx][1]]; // y-2
                float s3 = img[zo[wz][1] + yo[wy][1] + xo[wx][2]]; // x+2
                float s4 = img[zo[wz][2] + yo[wy][1] + xo[wx][1]]; // z+2
                float s5 = img[zo[wz][1] + yo[wy][2] + xo[wx][1]]; // y+2
                float d;
                d = s1 - s0; ssd[0]  += d * d;
                d = s2 - s0; ssd[1]  += d * d;
                d = s2 - s1; ssd[2]  += d * d;
                d = s3 - s0; ssd[3]  += d * d;
                d = s3 - s2; ssd[4]  += d * d;
                d = s4 - s1; ssd[5]  += d * d;
                d = s4 - s2; ssd[6]  += d * d;
                d = s4 - s3; ssd[7]  += d * d;
                d = s5 - s0; ssd[8]  += d * d;
                d = s5 - s1; ssd[9]  += d * d;
                d = s5 - s3; ssd[10] += d * d;
                d = s5 - s4; ssd[11] += d * d;
            }
}

__device__ __forceinline__ void block_reduce_atomic(float v, double* dst) {
#pragma unroll
    for (int off = 32; off > 0; off >>= 1)
        v += __shfl_down(v, off, 64);
    __shared__ float red[4];
    int lane = threadIdx.x & 63;
    int wid  = threadIdx.x >> 6;
    if (lane == 0) red[wid] = v;
    __syncthreads();
    if (threadIdx.x == 0) {
        double t = (double)red[0] + (double)red[1] + (double)red[2] + (double)red[3];
        atomicAdd(dst, t);
    }
}

// Pass 1: per-voxel mind_var = mean_c(ssd) - min_c(ssd); global sum per image.
__global__ __launch_bounds__(256) void var_kernel(const float* __restrict__ pred,
                                                  const float* __restrict__ targ,
                                                  double* __restrict__ sums) {
    const float* img = (blockIdx.y == 0) ? pred : targ;
    int idx = blockIdx.x * 256 + threadIdx.x;
    int x = idx & 127, y = (idx >> 7) & 127, z = (idx >> 14) & 127, n = idx >> 21;

    float ssd[12];
    compute_ssd(img + n * DHW, z, y, x, ssd);

    float mn = ssd[0], sm = ssd[0];
#pragma unroll
    for (int c = 1; c < 12; ++c) { mn = fminf(mn, ssd[c]); sm += ssd[c]; }
    float var = sm * (1.0f / 12.0f) - mn;

    block_reduce_atomic(var, &sums[blockIdx.y]);
}

// Pass 2: full MIND fields for both images at this voxel; squared-diff sum.
__global__ __launch_bounds__(256) void loss_kernel(const float* __restrict__ pred,
                                                   const float* __restrict__ targ,
                                                   const double* __restrict__ sums,
                                                   double* __restrict__ loss_sum) {
    int idx = blockIdx.x * 256 + threadIdx.x;
    int x = idx & 127, y = (idx >> 7) & 127, z = (idx >> 14) & 127, n = idx >> 21;
    int nb = n * DHW;

    float m_p = (float)(sums[0] * (1.0 / (double)NVOX));
    float m_t = (float)(sums[1] * (1.0 / (double)NVOX));

    float ssd[12], ep[12];

    compute_ssd(pred + nb, z, y, x, ssd);
    {
        float mn = ssd[0], sm = ssd[0];
#pragma unroll
        for (int c = 1; c < 12; ++c) { mn = fminf(mn, ssd[c]); sm += ssd[c]; }
        float var = sm * (1.0f / 12.0f) - mn;
        var = fminf(fmaxf(var, m_p * 0.001f), m_p * 1000.0f);
        float inv = -1.0f / var;
#pragma unroll
        for (int c = 0; c < 12; ++c) ep[c] = __expf((ssd[c] - mn) * inv);
    }

    compute_ssd(targ + nb, z, y, x, ssd);
    float acc = 0.0f;
    {
        float mn = ssd[0], sm = ssd[0];
#pragma unroll
        for (int c = 1; c < 12; ++c) { mn = fminf(mn, ssd[c]); sm += ssd[c]; }
        float var = sm * (1.0f / 12.0f) - mn;
        var = fminf(fmaxf(var, m_t * 0.001f), m_t * 1000.0f);
        float inv = -1.0f / var;
#pragma unroll
        for (int c = 0; c < 12; ++c) {
            float et = __expf((ssd[c] - mn) * inv);
            float dd = ep[c] - et;
            acc += dd * dd;
        }
    }

    block_reduce_atomic(acc, loss_sum);
}

__global__ void finalize_kernel(const double* __restrict__ loss_sum,
                                float* __restrict__ out) {
    out[0] = (float)(loss_sum[0] * (1.0 / LOSS_COUNT));
}

extern "C" void kernel_launch(void* const* d_in, const int* in_sizes, int n_in,
                              void* d_out, int out_size, void* d_ws, size_t ws_size,
                              hipStream_t stream) {
    const float* pred = (const float*)d_in[0];
    const float* targ = (const float*)d_in[1];
    float* out = (float*)d_out;
    double* acc = (double*)d_ws;   // [0]=sum_var_pred, [1]=sum_var_targ, [2]=loss_sum

    hipMemsetAsync(d_ws, 0, 3 * sizeof(double), stream);

    dim3 block(256);
    dim3 grid1(NVOX / 256, 2);
    var_kernel<<<grid1, block, 0, stream>>>(pred, targ, acc);

    dim3 grid2(NVOX / 256);
    loss_kernel<<<grid2, block, 0, stream>>>(pred, targ, acc, acc + 2);

    finalize_kernel<<<1, 1, 0, stream>>>(acc + 2, out);
}

// Round 2
// 398.950 us; speedup vs baseline: 2.8434x; 2.8434x over previous
//
#include <hip/hip_runtime.h>

// MIND-SSC loss, N=2, C=1, D=H=W=128, radius=1, dilation=2.
// Separable/shared evaluation:
//  - per z-plane, diff2[12ch] staged into LDS over an 18x18 halo plane
//  - 3x3 in-plane box summed from LDS (9 taps/ch), 3-tap z box via register ring
//  - nested clamps preserved: halo plane positions clamped (box edge-pad),
//    sample offsets +/-2 clamped again (dilation edge-pad)
//  - /27 dropped (exact: mind/var ratio and clip bounds jointly scale-invariant)

#define DIM 128
#define HW (128 * 128)
#define DHW (128 * 128 * 128)
#define NVOX (2 * DHW)            // voxels per tensor (N=2)
#define LOSS_COUNT (2.0 * 12.0 * DHW)

#define TS   16                   // tile side (y and x)
#define PR   18                   // plane positions per side (TS + 2 halo)
#define NP   (PR * PR)            // 324 plane positions
#define PROW 24                   // padded LDS row stride (uniform 2-way banks)
#define PCH  (PR * PROW)          // 432 words per channel plane
#define CHZ  32                   // z-chunk per block

__device__ __forceinline__ int clampi(int v) {
    v = v < 0 ? 0 : v;
    return v > 127 ? 127 : v;
}

__device__ __forceinline__ void block_reduce_atomic(float v, double* dst) {
#pragma unroll
    for (int off = 32; off > 0; off >>= 1)
        v += __shfl_down(v, off, 64);
    __shared__ float red[4];
    int lane = threadIdx.x & 63;
    int wid  = threadIdx.x >> 6;
    if (lane == 0) red[wid] = v;
    __syncthreads();
    if (threadIdx.x == 0) {
        double t = (double)red[0] + (double)red[1] + (double)red[2] + (double)red[3];
        atomicAdd(dst, t);
    }
    __syncthreads();
}

// Precomputed per-thread plane-position sampling offsets.
struct Pos {
    int y0, ym, yp;   // row offsets (gy, clamp(gy-2), clamp(gy+2)) * DIM
    int x0, xm, xp;   // col offsets
    int woff;         // LDS write offset within a channel plane
};

__device__ __forceinline__ Pos make_pos(int p, int y0t, int x0t) {
    Pos q;
    int py = p / PR, px = p % PR;
    int gy = clampi(y0t - 1 + py);
    int gx = clampi(x0t - 1 + px);
    q.y0 = gy * DIM; q.ym = clampi(gy - 2) * DIM; q.yp = clampi(gy + 2) * DIM;
    q.x0 = gx;       q.xm = clampi(gx - 2);       q.xp = clampi(gx + 2);
    q.woff = py * PROW + px;
    return q;
}

__device__ __forceinline__ void stage_pos(const float* __restrict__ im,
                                          int zm, int zc, int zp,
                                          const Pos& q, float* __restrict__ P) {
    float s0 = im[zm + q.y0 + q.x0];   // z-2
    float s1 = im[zc + q.y0 + q.xm];   // x-2
    float s2 = im[zc + q.ym + q.x0];   // y-2
    float s3 = im[zc + q.y0 + q.xp];   // x+2
    float s4 = im[zp + q.y0 + q.x0];   // z+2
    float s5 = im[zc + q.yp + q.x0];   // y+2
    float d;
    d = s1 - s0; P[ 0 * PCH + q.woff] = d * d;
    d = s2 - s0; P[ 1 * PCH + q.woff] = d * d;
    d = s2 - s1; P[ 2 * PCH + q.woff] = d * d;
    d = s3 - s0; P[ 3 * PCH + q.woff] = d * d;
    d = s3 - s2; P[ 4 * PCH + q.woff] = d * d;
    d = s4 - s1; P[ 5 * PCH + q.woff] = d * d;
    d = s4 - s2; P[ 6 * PCH + q.woff] = d * d;
    d = s4 - s3; P[ 7 * PCH + q.woff] = d * d;
    d = s5 - s0; P[ 8 * PCH + q.woff] = d * d;
    d = s5 - s1; P[ 9 * PCH + q.woff] = d * d;
    d = s5 - s3; P[10 * PCH + q.woff] = d * d;
    d = s5 - s4; P[11 * PCH + q.woff] = d * d;
}

__device__ __forceinline__ void box9(const float* __restrict__ P,
                                     int ty, int tx, float q[12]) {
#pragma unroll
    for (int c = 0; c < 12; ++c) {
        float s = 0.0f;
#pragma unroll
        for (int wy = 0; wy < 3; ++wy) {
            int r = c * PCH + (ty + wy) * PROW + tx;
#pragma unroll
            for (int wx = 0; wx < 3; ++wx) s += P[r + wx];
        }
        q[c] = s;
    }
}

// Pass 1: per-voxel mind_var = mean_c(ssd) - min_c(ssd); global sum per image.
__global__ __launch_bounds__(256) void var_kernel(const float* __restrict__ pred,
                                                  const float* __restrict__ targ,
                                                  double* __restrict__ sums) {
    __shared__ float P[12 * PCH];
    const int t = threadIdx.x;
    const int tile = blockIdx.x & 63, n = blockIdx.x >> 6;
    const int x0t = (tile & 7) * TS, y0t = (tile >> 3) * TS;
    const int z0 = blockIdx.y * CHZ;
    const float* img = ((blockIdx.z == 0) ? pred : targ) + (size_t)n * DHW;

    Pos pa = make_pos(t, y0t, x0t);
    const bool hasB = (t + 256) < NP;
    Pos pb = make_pos(hasB ? (t + 256) : 0, y0t, x0t);

    const int ty = t >> 4, tx = t & 15;

    float A[12], B[12];
#pragma unroll
    for (int c = 0; c < 12; ++c) { A[c] = 0.0f; B[c] = 0.0f; }
    float vsum = 0.0f;

    for (int tz = z0 - 1; tz <= z0 + CHZ; ++tz) {
        int zq = clampi(tz);
        int zc = zq * HW, zm = clampi(zq - 2) * HW, zp = clampi(zq + 2) * HW;
        stage_pos(img, zm, zc, zp, pa, P);
        if (hasB) stage_pos(img, zm, zc, zp, pb, P);
        __syncthreads();

        float q[12];
        box9(P, ty, tx, q);

        int ze = tz - 1;
        if (ze >= z0 && ze < z0 + CHZ) {
            float v0 = A[0] + q[0];
            float mn = v0, sm = v0;
#pragma unroll
            for (int c = 1; c < 12; ++c) {
                float v = A[c] + q[c];
                mn = fminf(mn, v); sm += v;
            }
            vsum += sm * (1.0f / 12.0f) - mn;
        }
#pragma unroll
        for (int c = 0; c < 12; ++c) { A[c] = B[c] + q[c]; B[c] = q[c]; }
        __syncthreads();
    }

    block_reduce_atomic(vsum, &sums[blockIdx.z]);
}

// Pass 2: both images' MIND at each voxel; squared-diff sum.
__global__ __launch_bounds__(256) void loss_kernel(const float* __restrict__ pred,
                                                   const float* __restrict__ targ,
                                                   const double* __restrict__ sums,
                                                   double* __restrict__ loss_sum) {
    __shared__ float P[12 * PCH];
    const int t = threadIdx.x;
    const int tile = blockIdx.x & 63, n = blockIdx.x >> 6;
    const int x0t = (tile & 7) * TS, y0t = (tile >> 3) * TS;
    const int z0 = blockIdx.y * CHZ;
    const float* ip = pred + (size_t)n * DHW;
    const float* tp = targ + (size_t)n * DHW;

    const float m_p = (float)(sums[0] * (1.0 / (double)NVOX));
    const float m_t = (float)(sums[1] * (1.0 / (double)NVOX));

    Pos pa = make_pos(t, y0t, x0t);
    const bool hasB = (t + 256) < NP;
    Pos pb = make_pos(hasB ? (t + 256) : 0, y0t, x0t);

    const int ty = t >> 4, tx = t & 15;

    float Ap[12], Bp[12], At[12], Bt[12];
#pragma unroll
    for (int c = 0; c < 12; ++c) { Ap[c] = Bp[c] = At[c] = Bt[c] = 0.0f; }
    float lsum = 0.0f;

    for (int tz = z0 - 1; tz <= z0 + CHZ; ++tz) {
        int zq = clampi(tz);
        int zc = zq * HW, zm = clampi(zq - 2) * HW, zp = clampi(zq + 2) * HW;

        stage_pos(ip, zm, zc, zp, pa, P);
        if (hasB) stage_pos(ip, zm, zc, zp, pb, P);
        __syncthreads();
        float qp[12];
        box9(P, ty, tx, qp);
        __syncthreads();

        stage_pos(tp, zm, zc, zp, pa, P);
        if (hasB) stage_pos(tp, zm, zc, zp, pb, P);
        __syncthreads();
        float qt[12];
        box9(P, ty, tx, qt);

        int ze = tz - 1;
        if (ze >= z0 && ze < z0 + CHZ) {
            // pred stats
            float v0 = Ap[0] + qp[0];
            float mnp = v0, smp = v0;
#pragma unroll
            for (int c = 1; c < 12; ++c) {
                float v = Ap[c] + qp[c];
                mnp = fminf(mnp, v); smp += v;
            }
            float varp = smp * (1.0f / 12.0f) - mnp;
            varp = fminf(fmaxf(varp, m_p * 0.001f), m_p * 1000.0f);
            float invp = -1.0f / varp;
            // targ stats
            v0 = At[0] + qt[0];
            float mnt = v0, smt = v0;
#pragma unroll
            for (int c = 1; c < 12; ++c) {
                float v = At[c] + qt[c];
                mnt = fminf(mnt, v); smt += v;
            }
            float vart = smt * (1.0f / 12.0f) - mnt;
            vart = fminf(fmaxf(vart, m_t * 0.001f), m_t * 1000.0f);
            float invt = -1.0f / vart;

            float acc = 0.0f;
#pragma unroll
            for (int c = 0; c < 12; ++c) {
                float ep = __expf((Ap[c] + qp[c] - mnp) * invp);
                float et = __expf((At[c] + qt[c] - mnt) * invt);
                float dd = ep - et;
                acc += dd * dd;
            }
            lsum += acc;
        }
#pragma unroll
        for (int c = 0; c < 12; ++c) {
            Ap[c] = Bp[c] + qp[c]; Bp[c] = qp[c];
            At[c] = Bt[c] + qt[c]; Bt[c] = qt[c];
        }
        __syncthreads();
    }

    block_reduce_atomic(lsum, loss_sum);
}

__global__ void finalize_kernel(const double* __restrict__ loss_sum,
                                float* __restrict__ out) {
    out[0] = (float)(loss_sum[0] * (1.0 / LOSS_COUNT));
}

extern "C" void kernel_launch(void* const* d_in, const int* in_sizes, int n_in,
                              void* d_out, int out_size, void* d_ws, size_t ws_size,
                              hipStream_t stream) {
    const float* pred = (const float*)d_in[0];
    const float* targ = (const float*)d_in[1];
    float* out = (float*)d_out;
    double* acc = (double*)d_ws;   // [0]=sum_var_pred, [1]=sum_var_targ, [2]=loss_sum

    hipMemsetAsync(d_ws, 0, 3 * sizeof(double), stream);

    dim3 block(256);
    var_kernel<<<dim3(128, 4, 2), block, 0, stream>>>(pred, targ, acc);
    loss_kernel<<<dim3(128, 4), block, 0, stream>>>(pred, targ, acc, acc + 2);
    finalize_kernel<<<1, 1, 0, stream>>>(acc + 2, out);
}

// Round 3
// 255.944 us; speedup vs baseline: 4.4322x; 1.5587x over previous
//
#include <hip/hip_runtime.h>

// MIND-SSC loss, N=2, C=1, D=H=W=128, radius=1, dilation=2.
// Round 3: channel-interleaved float4 LDS layout.
//  - diff2[12] stored as 3 x float4 per plane position -> ds_read_b128/ds_write_b128
//  - lane stride 12 words: every 8 lanes' b128 accesses tile all 32 banks once
//    (conflict-free); row stride 216 words === 24 mod 32 keeps the pattern
//  - 3x3 in-plane box = 27 b128 reads/voxel-image (was 108 b32)
//  - z-box via register ring; nested clamps preserved; /27 dropped (exact)

#define DIM 128
#define HW (128 * 128)
#define DHW (128 * 128 * 128)
#define NVOX (2 * DHW)
#define LOSS_COUNT (2.0 * 12.0 * DHW)

#define TS   16                   // tile side (y and x)
#define PR   18                   // plane side incl. halo
#define NP   (PR * PR)            // 324 plane positions
#define CHZ  16                   // z-chunk per block

typedef float f4 __attribute__((ext_vector_type(4)));

__device__ __forceinline__ int clampi(int v) {
    v = v < 0 ? 0 : v;
    return v > 127 ? 127 : v;
}

__device__ __forceinline__ void block_reduce_atomic(float v, double* dst) {
#pragma unroll
    for (int off = 32; off > 0; off >>= 1)
        v += __shfl_down(v, off, 64);
    __shared__ float red[4];
    int lane = threadIdx.x & 63;
    int wid  = threadIdx.x >> 6;
    if (lane == 0) red[wid] = v;
    __syncthreads();
    if (threadIdx.x == 0) {
        double t = (double)red[0] + (double)red[1] + (double)red[2] + (double)red[3];
        atomicAdd(dst, t);
    }
    __syncthreads();
}

struct Pos {
    int y0, ym, yp;   // row offsets * DIM (center, clamp(-2), clamp(+2))
    int x0, xm, xp;   // col offsets
    int woff3;        // f4 index of this position's quad triple
};

__device__ __forceinline__ Pos make_pos(int p, int y0t, int x0t) {
    Pos q;
    int py = p / PR, px = p % PR;
    int gy = clampi(y0t - 1 + py);
    int gx = clampi(x0t - 1 + px);
    q.y0 = gy * DIM; q.ym = clampi(gy - 2) * DIM; q.yp = clampi(gy + 2) * DIM;
    q.x0 = gx;       q.xm = clampi(gx - 2);       q.xp = clampi(gx + 2);
    q.woff3 = (py * PR + px) * 3;
    return q;
}

__device__ __forceinline__ void stage_pos(const float* __restrict__ im,
                                          int zm, int zc, int zp,
                                          const Pos& q, f4* __restrict__ P) {
    float s0 = im[zm + q.y0 + q.x0];   // z-2
    float s1 = im[zc + q.y0 + q.xm];   // x-2
    float s2 = im[zc + q.ym + q.x0];   // y-2
    float s3 = im[zc + q.y0 + q.xp];   // x+2
    float s4 = im[zp + q.y0 + q.x0];   // z+2
    float s5 = im[zc + q.yp + q.x0];   // y+2
    f4 a, b, c;
    float d;
    d = s1 - s0; a.x = d * d;
    d = s2 - s0; a.y = d * d;
    d = s2 - s1; a.z = d * d;
    d = s3 - s0; a.w = d * d;
    d = s3 - s2; b.x = d * d;
    d = s4 - s1; b.y = d * d;
    d = s4 - s2; b.z = d * d;
    d = s4 - s3; b.w = d * d;
    d = s5 - s0; c.x = d * d;
    d = s5 - s1; c.y = d * d;
    d = s5 - s3; c.z = d * d;
    d = s5 - s4; c.w = d * d;
    P[q.woff3 + 0] = a;
    P[q.woff3 + 1] = b;
    P[q.woff3 + 2] = c;
}

__device__ __forceinline__ void box9(const f4* __restrict__ P,
                                     int ty, int tx, f4 q[3]) {
    q[0] = (f4)0.0f; q[1] = (f4)0.0f; q[2] = (f4)0.0f;
#pragma unroll
    for (int wy = 0; wy < 3; ++wy) {
#pragma unroll
        for (int wx = 0; wx < 3; ++wx) {
            int b = ((ty + wy) * PR + (tx + wx)) * 3;
            q[0] += P[b + 0];
            q[1] += P[b + 1];
            q[2] += P[b + 2];
        }
    }
}

// mean - min over the 12 channels held in v[3] quads (un-normalized ssd).
__device__ __forceinline__ float mind_var_of(const f4 v[3]) {
    float mn = v[0][0], sm = 0.0f;
#pragma unroll
    for (int i = 0; i < 4; ++i) {
        sm += v[0][i] + v[1][i] + v[2][i];
        mn = fminf(mn, fminf(v[0][i], fminf(v[1][i], v[2][i])));
    }
    return sm * (1.0f / 12.0f) - mn;
}

// Pass 1: per-voxel mind_var for BOTH images; global sums.
__global__ __launch_bounds__(256) void var_kernel(const float* __restrict__ pred,
                                                  const float* __restrict__ targ,
                                                  double* __restrict__ sums) {
    __shared__ f4 Pp[NP * 3];
    __shared__ f4 Pt[NP * 3];
    const int t = threadIdx.x;
    const int tile = blockIdx.x & 63, n = blockIdx.x >> 6;
    const int x0t = (tile & 7) * TS, y0t = (tile >> 3) * TS;
    const int z0 = blockIdx.y * CHZ;
    const float* ip = pred + (size_t)n * DHW;
    const float* tp = targ + (size_t)n * DHW;

    Pos pa = make_pos(t, y0t, x0t);
    const bool hasB = (t + 256) < NP;
    Pos pb = make_pos(hasB ? (t + 256) : 0, y0t, x0t);

    const int ty = t >> 4, tx = t & 15;

    f4 Ap[3], Bp[3], At[3], Bt[3];
#pragma unroll
    for (int q = 0; q < 3; ++q) {
        Ap[q] = (f4)0.0f; Bp[q] = (f4)0.0f;
        At[q] = (f4)0.0f; Bt[q] = (f4)0.0f;
    }
    float vsump = 0.0f, vsumt = 0.0f;

    for (int tz = z0 - 1; tz <= z0 + CHZ; ++tz) {
        int zq = clampi(tz);
        int zc = zq * HW, zm = clampi(zq - 2) * HW, zp = clampi(zq + 2) * HW;
        stage_pos(ip, zm, zc, zp, pa, Pp);
        stage_pos(tp, zm, zc, zp, pa, Pt);
        if (hasB) {
            stage_pos(ip, zm, zc, zp, pb, Pp);
            stage_pos(tp, zm, zc, zp, pb, Pt);
        }
        __syncthreads();

        f4 qp[3], qt[3];
        box9(Pp, ty, tx, qp);
        box9(Pt, ty, tx, qt);
        __syncthreads();

        int ze = tz - 1;
        if (ze >= z0) {
            f4 vp[3], vt[3];
#pragma unroll
            for (int q = 0; q < 3; ++q) {
                vp[q] = Ap[q] + qp[q];
                vt[q] = At[q] + qt[q];
            }
            vsump += mind_var_of(vp);
            vsumt += mind_var_of(vt);
        }
#pragma unroll
        for (int q = 0; q < 3; ++q) {
            Ap[q] = Bp[q] + qp[q]; Bp[q] = qp[q];
            At[q] = Bt[q] + qt[q]; Bt[q] = qt[q];
        }
    }

    block_reduce_atomic(vsump, &sums[0]);
    block_reduce_atomic(vsumt, &sums[1]);
}

// Pass 2: both images' MIND at each voxel; squared-diff sum.
__global__ __launch_bounds__(256) void loss_kernel(const float* __restrict__ pred,
                                                   const float* __restrict__ targ,
                                                   const double* __restrict__ sums,
                                                   double* __restrict__ loss_sum) {
    __shared__ f4 Pp[NP * 3];
    __shared__ f4 Pt[NP * 3];
    const int t = threadIdx.x;
    const int tile = blockIdx.x & 63, n = blockIdx.x >> 6;
    const int x0t = (tile & 7) * TS, y0t = (tile >> 3) * TS;
    const int z0 = blockIdx.y * CHZ;
    const float* ip = pred + (size_t)n * DHW;
    const float* tp = targ + (size_t)n * DHW;

    const float m_p = (float)(sums[0] * (1.0 / (double)NVOX));
    const float m_t = (float)(sums[1] * (1.0 / (double)NVOX));

    Pos pa = make_pos(t, y0t, x0t);
    const bool hasB = (t + 256) < NP;
    Pos pb = make_pos(hasB ? (t + 256) : 0, y0t, x0t);

    const int ty = t >> 4, tx = t & 15;

    f4 Ap[3], Bp[3], At[3], Bt[3];
#pragma unroll
    for (int q = 0; q < 3; ++q) {
        Ap[q] = (f4)0.0f; Bp[q] = (f4)0.0f;
        At[q] = (f4)0.0f; Bt[q] = (f4)0.0f;
    }
    float lsum = 0.0f;

    for (int tz = z0 - 1; tz <= z0 + CHZ; ++tz) {
        int zq = clampi(tz);
        int zc = zq * HW, zm = clampi(zq - 2) * HW, zp = clampi(zq + 2) * HW;
        stage_pos(ip, zm, zc, zp, pa, Pp);
        stage_pos(tp, zm, zc, zp, pa, Pt);
        if (hasB) {
            stage_pos(ip, zm, zc, zp, pb, Pp);
            stage_pos(tp, zm, zc, zp, pb, Pt);
        }
        __syncthreads();

        f4 qp[3], qt[3];
        box9(Pp, ty, tx, qp);
        box9(Pt, ty, tx, qt);
        __syncthreads();

        int ze = tz - 1;
        if (ze >= z0) {
            f4 vp[3], vt[3];
#pragma unroll
            for (int q = 0; q < 3; ++q) {
                vp[q] = Ap[q] + qp[q];
                vt[q] = At[q] + qt[q];
            }
            // pred stats
            float mnp = vp[0][0], smp = 0.0f;
            float mnt = vt[0][0], smt = 0.0f;
#pragma unroll
            for (int i = 0; i < 4; ++i) {
                smp += vp[0][i] + vp[1][i] + vp[2][i];
                mnp = fminf(mnp, fminf(vp[0][i], fminf(vp[1][i], vp[2][i])));
                smt += vt[0][i] + vt[1][i] + vt[2][i];
                mnt = fminf(mnt, fminf(vt[0][i], fminf(vt[1][i], vt[2][i])));
            }
            float varp = smp * (1.0f / 12.0f) - mnp;
            varp = fminf(fmaxf(varp, m_p * 0.001f), m_p * 1000.0f);
            float invp = -1.0f / varp;
            float vart = smt * (1.0f / 12.0f) - mnt;
            vart = fminf(fmaxf(vart, m_t * 0.001f), m_t * 1000.0f);
            float invt = -1.0f / vart;

            float acc = 0.0f;
#pragma unroll
            for (int q = 0; q < 3; ++q)
#pragma unroll
                for (int i = 0; i < 4; ++i) {
                    float ep = __expf((vp[q][i] - mnp) * invp);
                    float et = __expf((vt[q][i] - mnt) * invt);
                    float dd = ep - et;
                    acc += dd * dd;
                }
            lsum += acc;
        }
#pragma unroll
        for (int q = 0; q < 3; ++q) {
            Ap[q] = Bp[q] + qp[q]; Bp[q] = qp[q];
            At[q] = Bt[q] + qt[q]; Bt[q] = qt[q];
        }
    }

    block_reduce_atomic(lsum, loss_sum);
}

__global__ void finalize_kernel(const double* __restrict__ loss_sum,
                                float* __restrict__ out) {
    out[0] = (float)(loss_sum[0] * (1.0 / LOSS_COUNT));
}

extern "C" void kernel_launch(void* const* d_in, const int* in_sizes, int n_in,
                              void* d_out, int out_size, void* d_ws, size_t ws_size,
                              hipStream_t stream) {
    const float* pred = (const float*)d_in[0];
    const float* targ = (const float*)d_in[1];
    float* out = (float*)d_out;
    double* acc = (double*)d_ws;   // [0]=sum_var_pred, [1]=sum_var_targ, [2]=loss_sum

    hipMemsetAsync(d_ws, 0, 3 * sizeof(double), stream);

    dim3 block(256);
    dim3 grid(128, 8);   // 64 tiles * 2 batch, 8 z-chunks of 16
    var_kernel<<<grid, block, 0, stream>>>(pred, targ, acc);
    loss_kernel<<<grid, block, 0, stream>>>(pred, targ, acc, acc + 2);
    finalize_kernel<<<1, 1, 0, stream>>>(acc + 2, out);
}

// Round 4
// 236.836 us; speedup vs baseline: 4.7898x; 1.0807x over previous
//
#include <hip/hip_runtime.h>

// MIND-SSC loss, N=2, C=1, D=H=W=128, radius=1, dilation=2.
// Round 4: x-folded staging.
//  - stagers compute xsum(x,y) = sum_{wx} diff2(clamp(x+wx), y) straight from
//    global memory (18 scalar L1-hit loads/position) and write 3 f4 to LDS
//  - readers do only 3 y-taps (9 ds_read_b128/voxel-image); z via register ring
//  - LDS ops/plane cut 2.5x vs round 3 (the measured bottleneck)
//  - nested clamps preserved exactly; /27 dropped (exact: scale-invariant)

#define DIM 128
#define HW (128 * 128)
#define DHW (128 * 128 * 128)
#define NVOX (2 * DHW)
#define LOSS_COUNT (2.0 * 12.0 * DHW)

#define TS   16                   // tile side (y and x)
#define SY   18                   // xsum rows incl. y halo
#define NSP  (SY * TS)            // 288 xsum positions
#define CHZ  16                   // z-chunk per block

typedef float f4 __attribute__((ext_vector_type(4)));

__device__ __forceinline__ int clampi(int v) {
    v = v < 0 ? 0 : v;
    return v > 127 ? 127 : v;
}

__device__ __forceinline__ void block_reduce_atomic(float v, double* dst) {
#pragma unroll
    for (int off = 32; off > 0; off >>= 1)
        v += __shfl_down(v, off, 64);
    __shared__ float red[4];
    int lane = threadIdx.x & 63;
    int wid  = threadIdx.x >> 6;
    if (lane == 0) red[wid] = v;
    __syncthreads();
    if (threadIdx.x == 0) {
        double t = (double)red[0] + (double)red[1] + (double)red[2] + (double)red[3];
        atomicAdd(dst, t);
    }
    __syncthreads();
}

// Per-thread staging descriptor: one xsum position (px in [0,16), py in [0,18)).
struct SPos {
    int y0, ym, yp;        // row offsets * DIM: gy, clamp(gy-2), clamp(gy+2)
    int cx[3], cm[3], cp[3]; // per-wx tap columns: c, clamp(c-2), clamp(c+2)
    int woff3;             // f4 index of this position's quad triple
};

__device__ __forceinline__ SPos make_spos(int p, int y0t, int x0t) {
    SPos q;
    int py = p >> 4, px = p & 15;
    int gy = clampi(y0t - 1 + py);
    int gx = x0t + px;                 // output-tile column, always in [0,128)
    q.y0 = gy * DIM; q.ym = clampi(gy - 2) * DIM; q.yp = clampi(gy + 2) * DIM;
#pragma unroll
    for (int wx = 0; wx < 3; ++wx) {
        int c = clampi(gx + wx - 1);   // box tap clamp (outer pad)
        q.cx[wx] = c;
        q.cm[wx] = clampi(c - 2);      // dilation clamp (inner pad)
        q.cp[wx] = clampi(c + 2);
    }
    q.woff3 = p * 3;
    return q;
}

// Compute xsum (3-tap x box of diff2) at this position; write 3 f4 to LDS.
__device__ __forceinline__ void stage_xsum(const float* __restrict__ im,
                                           int zm, int zc, int zp,
                                           const SPos& q, f4* __restrict__ P) {
    f4 a = (f4)0.0f, b = (f4)0.0f, c = (f4)0.0f;
#pragma unroll
    for (int wx = 0; wx < 3; ++wx) {
        float s0 = im[zm + q.y0 + q.cx[wx]];   // z-2
        float s1 = im[zc + q.y0 + q.cm[wx]];   // x-2
        float s2 = im[zc + q.ym + q.cx[wx]];   // y-2
        float s3 = im[zc + q.y0 + q.cp[wx]];   // x+2
        float s4 = im[zp + q.y0 + q.cx[wx]];   // z+2
        float s5 = im[zc + q.yp + q.cx[wx]];   // y+2
        float d;
        d = s1 - s0; a.x += d * d;
        d = s2 - s0; a.y += d * d;
        d = s2 - s1; a.z += d * d;
        d = s3 - s0; a.w += d * d;
        d = s3 - s2; b.x += d * d;
        d = s4 - s1; b.y += d * d;
        d = s4 - s2; b.z += d * d;
        d = s4 - s3; b.w += d * d;
        d = s5 - s0; c.x += d * d;
        d = s5 - s1; c.y += d * d;
        d = s5 - s3; c.z += d * d;
        d = s5 - s4; c.w += d * d;
    }
    P[q.woff3 + 0] = a;
    P[q.woff3 + 1] = b;
    P[q.woff3 + 2] = c;
}

// 3-tap y box of staged xsums -> full in-plane 3x3 box.
__device__ __forceinline__ void box3y(const f4* __restrict__ P,
                                      int ty, int tx, f4 q[3]) {
    int base = (ty * TS + tx) * 3;
#pragma unroll
    for (int k = 0; k < 3; ++k)
        q[k] = P[base + k] + P[base + TS * 3 + k] + P[base + 2 * TS * 3 + k];
}

__device__ __forceinline__ float mind_var_of(const f4 v[3]) {
    float mn = v[0][0], sm = 0.0f;
#pragma unroll
    for (int i = 0; i < 4; ++i) {
        sm += v[0][i] + v[1][i] + v[2][i];
        mn = fminf(mn, fminf(v[0][i], fminf(v[1][i], v[2][i])));
    }
    return sm * (1.0f / 12.0f) - mn;
}

// Pass 1: per-voxel mind_var for both images; global sums.
__global__ __launch_bounds__(256, 4) void var_kernel(const float* __restrict__ pred,
                                                     const float* __restrict__ targ,
                                                     double* __restrict__ sums) {
    __shared__ f4 Xp[NSP * 3];
    __shared__ f4 Xt[NSP * 3];
    const int t = threadIdx.x;
    const int tile = blockIdx.x & 63, n = blockIdx.x >> 6;
    const int x0t = (tile & 7) * TS, y0t = (tile >> 3) * TS;
    const int z0 = blockIdx.y * CHZ;
    const float* ip = pred + (size_t)n * DHW;
    const float* tp = targ + (size_t)n * DHW;

    SPos pa = make_spos(t, y0t, x0t);
    const bool hasB = (t + 256) < NSP;
    SPos pb = make_spos(hasB ? (t + 256) : 0, y0t, x0t);

    const int ty = t >> 4, tx = t & 15;

    f4 Ap[3], Bp[3], At[3], Bt[3];
#pragma unroll
    for (int q = 0; q < 3; ++q) {
        Ap[q] = (f4)0.0f; Bp[q] = (f4)0.0f;
        At[q] = (f4)0.0f; Bt[q] = (f4)0.0f;
    }
    float vsump = 0.0f, vsumt = 0.0f;

    for (int tz = z0 - 1; tz <= z0 + CHZ; ++tz) {
        int zq = clampi(tz);
        int zc = zq * HW, zm = clampi(zq - 2) * HW, zp = clampi(zq + 2) * HW;
        stage_xsum(ip, zm, zc, zp, pa, Xp);
        stage_xsum(tp, zm, zc, zp, pa, Xt);
        if (hasB) {
            stage_xsum(ip, zm, zc, zp, pb, Xp);
            stage_xsum(tp, zm, zc, zp, pb, Xt);
        }
        __syncthreads();

        f4 qp[3], qt[3];
        box3y(Xp, ty, tx, qp);
        box3y(Xt, ty, tx, qt);
        __syncthreads();

        int ze = tz - 1;
        if (ze >= z0) {
            f4 vp[3], vt[3];
#pragma unroll
            for (int q = 0; q < 3; ++q) {
                vp[q] = Ap[q] + qp[q];
                vt[q] = At[q] + qt[q];
            }
            vsump += mind_var_of(vp);
            vsumt += mind_var_of(vt);
        }
#pragma unroll
        for (int q = 0; q < 3; ++q) {
            Ap[q] = Bp[q] + qp[q]; Bp[q] = qp[q];
            At[q] = Bt[q] + qt[q]; Bt[q] = qt[q];
        }
    }

    block_reduce_atomic(vsump, &sums[0]);
    block_reduce_atomic(vsumt, &sums[1]);
}

// Pass 2: both images' MIND per voxel; squared-diff sum.
__global__ __launch_bounds__(256, 4) void loss_kernel(const float* __restrict__ pred,
                                                      const float* __restrict__ targ,
                                                      const double* __restrict__ sums,
                                                      double* __restrict__ loss_sum) {
    __shared__ f4 Xp[NSP * 3];
    __shared__ f4 Xt[NSP * 3];
    const int t = threadIdx.x;
    const int tile = blockIdx.x & 63, n = blockIdx.x >> 6;
    const int x0t = (tile & 7) * TS, y0t = (tile >> 3) * TS;
    const int z0 = blockIdx.y * CHZ;
    const float* ip = pred + (size_t)n * DHW;
    const float* tp = targ + (size_t)n * DHW;

    const float m_p = (float)(sums[0] * (1.0 / (double)NVOX));
    const float m_t = (float)(sums[1] * (1.0 / (double)NVOX));

    SPos pa = make_spos(t, y0t, x0t);
    const bool hasB = (t + 256) < NSP;
    SPos pb = make_spos(hasB ? (t + 256) : 0, y0t, x0t);

    const int ty = t >> 4, tx = t & 15;

    f4 Ap[3], Bp[3], At[3], Bt[3];
#pragma unroll
    for (int q = 0; q < 3; ++q) {
        Ap[q] = (f4)0.0f; Bp[q] = (f4)0.0f;
        At[q] = (f4)0.0f; Bt[q] = (f4)0.0f;
    }
    float lsum = 0.0f;

    for (int tz = z0 - 1; tz <= z0 + CHZ; ++tz) {
        int zq = clampi(tz);
        int zc = zq * HW, zm = clampi(zq - 2) * HW, zp = clampi(zq + 2) * HW;
        stage_xsum(ip, zm, zc, zp, pa, Xp);
        stage_xsum(tp, zm, zc, zp, pa, Xt);
        if (hasB) {
            stage_xsum(ip, zm, zc, zp, pb, Xp);
            stage_xsum(tp, zm, zc, zp, pb, Xt);
        }
        __syncthreads();

        f4 qp[3], qt[3];
        box3y(Xp, ty, tx, qp);
        box3y(Xt, ty, tx, qt);
        __syncthreads();

        int ze = tz - 1;
        if (ze >= z0) {
            f4 vp[3], vt[3];
#pragma unroll
            for (int q = 0; q < 3; ++q) {
                vp[q] = Ap[q] + qp[q];
                vt[q] = At[q] + qt[q];
            }
            float mnp = vp[0][0], smp = 0.0f;
            float mnt = vt[0][0], smt = 0.0f;
#pragma unroll
            for (int i = 0; i < 4; ++i) {
                smp += vp[0][i] + vp[1][i] + vp[2][i];
                mnp = fminf(mnp, fminf(vp[0][i], fminf(vp[1][i], vp[2][i])));
                smt += vt[0][i] + vt[1][i] + vt[2][i];
                mnt = fminf(mnt, fminf(vt[0][i], fminf(vt[1][i], vt[2][i])));
            }
            float varp = smp * (1.0f / 12.0f) - mnp;
            varp = fminf(fmaxf(varp, m_p * 0.001f), m_p * 1000.0f);
            float invp = -1.0f / varp;
            float vart = smt * (1.0f / 12.0f) - mnt;
            vart = fminf(fmaxf(vart, m_t * 0.001f), m_t * 1000.0f);
            float invt = -1.0f / vart;

            float acc = 0.0f;
#pragma unroll
            for (int q = 0; q < 3; ++q)
#pragma unroll
                for (int i = 0; i < 4; ++i) {
                    float ep = __expf((vp[q][i] - mnp) * invp);
                    float et = __expf((vt[q][i] - mnt) * invt);
                    float dd = ep - et;
                    acc += dd * dd;
                }
            lsum += acc;
        }
#pragma unroll
        for (int q = 0; q < 3; ++q) {
            Ap[q] = Bp[q] + qp[q]; Bp[q] = qp[q];
            At[q] = Bt[q] + qt[q]; Bt[q] = qt[q];
        }
    }

    block_reduce_atomic(lsum, loss_sum);
}

__global__ void finalize_kernel(const double* __restrict__ loss_sum,
                                float* __restrict__ out) {
    out[0] = (float)(loss_sum[0] * (1.0 / LOSS_COUNT));
}

extern "C" void kernel_launch(void* const* d_in, const int* in_sizes, int n_in,
                              void* d_out, int out_size, void* d_ws, size_t ws_size,
                              hipStream_t stream) {
    const float* pred = (const float*)d_in[0];
    const float* targ = (const float*)d_in[1];
    float* out = (float*)d_out;
    double* acc = (double*)d_ws;   // [0]=sum_var_pred, [1]=sum_var_targ, [2]=loss_sum

    hipMemsetAsync(d_ws, 0, 3 * sizeof(double), stream);

    dim3 block(256);
    dim3 grid(128, 8);   // 64 tiles * 2 batch, 8 z-chunks of 16
    var_kernel<<<grid, block, 0, stream>>>(pred, targ, acc);
    loss_kernel<<<grid, block, 0, stream>>>(pred, targ, acc, acc + 2);
    finalize_kernel<<<1, 1, 0, stream>>>(acc + 2, out);
}